// Round 8
// baseline (320.517 us; speedup 1.0000x reference)
//
#include <hip/hip_runtime.h>
#include <hip/hip_bf16.h>

// GIN encoder: out = BN_train( (x + scatter_sum(x[src]->dst)) @ W^T + b ), b cancels in BN.
// N=50000, F=H=512, E=160000.
// R12 = R11 resubmitted verbatim (R11 bench died to "container failed twice" —
//      infra, not kernel: full address/bounds/swizzle/sync audit found no fault).
// R11: gemm 256x256/16w/1blk-per-CU -> 128x256/8w/BK=32/48KB LDS -> 2 blocks/CU
//      (__launch_bounds__(512,4)). R10's 1-blk residency left every barrier
//      drain unhidden; 2-deep blocks backfill the stalls (m97 lesson). New
//      BK=32 XOR swizzle: LDS[r][c]=global[r][c^swz2(r)], swz2=(r&3)^((r>>2)&3),
//      verified 2-way-max bank aliasing (free). Per-wave compute (64x64,
//      acc[4][4], frag math) identical to verified R9/R10.
// ws: hb[N*512 bf16] | Wb[512*512 bf16] | s1|s2|scale|shift | flag | bsum[64] |
//     deg[N] cursor[N] offs[N+1] srcbuf[E] | union{ xb | zb }[N*512 bf16]  (~105 MB)

typedef __attribute__((ext_vector_type(8))) short short8;
typedef __attribute__((ext_vector_type(4))) float floatx4;

static __device__ __forceinline__ unsigned short f2bf(float f) {
    unsigned int u = __float_as_uint(f);
    u += 0x7FFFu + ((u >> 16) & 1u);   // round-to-nearest-even
    return (unsigned short)(u >> 16);
}

static __device__ __forceinline__ float bf2f(unsigned short v) {
    return __uint_as_float((unsigned)v << 16);
}

static __device__ __forceinline__ void gload16(const void* g, void* l) {
    __builtin_amdgcn_global_load_lds(
        (const __attribute__((address_space(1))) unsigned int*)g,
        (__attribute__((address_space(3))) unsigned int*)l, 16, 0, 0);
}

// ---- detect whether edge_index is int64 (odd int32 words all zero) or int32 ----
__global__ void detect_dtype(const int* __restrict__ ei, int* __restrict__ flag) {
    __shared__ int any_nz;
    if (threadIdx.x == 0) any_nz = 0;
    __syncthreads();
    if (ei[2 * threadIdx.x + 1] != 0) atomicOr(&any_nz, 1);
    __syncthreads();
    if (threadIdx.x == 0) *flag = (any_nz == 0) ? 1 : 0;  // 1 => int64 layout
}

static __device__ __forceinline__ void load_edge(const int* ei, int flag, int E, int e,
                                                 int& s, int& d) {
    if (flag) {
        const long long* e64 = (const long long*)ei;
        s = (int)e64[e];
        d = (int)e64[E + e];
    } else {
        s = ei[e];
        d = ei[E + e];
    }
}

// ---- W fp32 -> bf16, zero stats + deg/cursor ----
__global__ __launch_bounds__(256) void conv_w(const float* __restrict__ W,
                                              unsigned short* __restrict__ Wb,
                                              float* __restrict__ stats /*1024 floats*/,
                                              int* __restrict__ dz, int ndz) {
    int i = blockIdx.x * 256 + threadIdx.x;   // 65536 threads x 4 elems = 512*512
    float4 v = ((const float4*)W)[i];
    ushort4 u;
    u.x = f2bf(v.x); u.y = f2bf(v.y); u.z = f2bf(v.z); u.w = f2bf(v.w);
    ((ushort4*)Wb)[i] = u;
    if (blockIdx.x == 0) {
        stats[threadIdx.x] = 0.f;
        stats[256 + threadIdx.x] = 0.f;
        stats[512 + threadIdx.x] = 0.f;
        stats[768 + threadIdx.x] = 0.f;
    }
    for (int k = i; k < ndz; k += 65536) dz[k] = 0;
}

// ---- x fp32 -> bf16 (xb), streaming; 8 elems/thread ----
__global__ __launch_bounds__(256) void conv_x(const float* __restrict__ x,
                                              unsigned short* __restrict__ xb, int n8) {
    int i = blockIdx.x * 256 + threadIdx.x;
    if (i >= n8) return;
    float4 v0 = ((const float4*)x)[2 * i];
    float4 v1 = ((const float4*)x)[2 * i + 1];
    short8 o;
    o[0] = (short)f2bf(v0.x); o[1] = (short)f2bf(v0.y);
    o[2] = (short)f2bf(v0.z); o[3] = (short)f2bf(v0.w);
    o[4] = (short)f2bf(v1.x); o[5] = (short)f2bf(v1.y);
    o[6] = (short)f2bf(v1.z); o[7] = (short)f2bf(v1.w);
    ((short8*)xb)[i] = o;
}

// ---- per-dst degree count ----
__global__ __launch_bounds__(256) void deg_count(const int* __restrict__ ei,
                                                 const int* __restrict__ flag,
                                                 int* __restrict__ deg, int E, int N) {
    int e = blockIdx.x * 256 + threadIdx.x;
    if (e >= E) return;
    int s, d;
    load_edge(ei, *flag, E, e, s, d);
    if ((unsigned)d < (unsigned)N) atomicAdd(&deg[d], 1);
}

// ---- grid scan, part 1: per-block LDS scan of 1024-elem chunk ----
__global__ __launch_bounds__(1024) void scan_blk(const int* __restrict__ deg,
                                                 int* __restrict__ offs,
                                                 int* __restrict__ bsum, int N) {
    __shared__ int s[1024];
    int t = threadIdx.x;
    int g = blockIdx.x * 1024 + t;
    int v = (g < N) ? deg[g] : 0;
    s[t] = v;
    __syncthreads();
    for (int d = 1; d < 1024; d <<= 1) {
        int u = (t >= d) ? s[t - d] : 0;
        __syncthreads();
        s[t] += u;
        __syncthreads();
    }
    if (g < N) offs[g] = s[t] - v;          // exclusive, missing block offset
    if (t == 1023) bsum[blockIdx.x] = s[1023];
}

// ---- grid scan, part 2: add prefix of block sums (wave-0 butterfly) ----
__global__ __launch_bounds__(1024) void scan_fin(int* __restrict__ offs,
                                                 const int* __restrict__ bsum,
                                                 int N, int nb) {
    __shared__ int sh_pre, sh_tot;
    int t = threadIdx.x, b = blockIdx.x;
    if (t < 64) {                            // one full wave; nb <= 64
        int v = (t < nb) ? bsum[t] : 0;
        int p = (t < b) ? v : 0;
#pragma unroll
        for (int d = 1; d < 64; d <<= 1) { p += __shfl_xor(p, d); v += __shfl_xor(v, d); }
        if (t == 0) { sh_pre = p; sh_tot = v; }
    }
    __syncthreads();
    int g = b * 1024 + t;
    if (g < N) offs[g] += sh_pre;
    if (b == nb - 1 && t == 0) offs[N] = sh_tot;
}

// ---- scatter src indices into dst buckets ----
__global__ __launch_bounds__(256) void bucket_fill(const int* __restrict__ ei,
                                                   const int* __restrict__ flag,
                                                   const int* __restrict__ offs,
                                                   int* __restrict__ cursor,
                                                   int* __restrict__ srcbuf, int E, int N) {
    int e = blockIdx.x * 256 + threadIdx.x;
    if (e >= E) return;
    int s, d;
    load_edge(ei, *flag, E, e, s, d);
    if ((unsigned)d >= (unsigned)N || (unsigned)s >= (unsigned)N) return;
    int pos = offs[d] + atomicAdd(&cursor[d], 1);
    srcbuf[pos] = s;
}

// ---- h[n] = bf16( xb[n] + sum_{s in bucket(n)} xb[s] ), fp32 accum.
//      One wave per row: 64 lanes x 8 bf16 = 1024 B per row read, coalesced.
//      Gathers hit L3 (xb = 51.2 MB fully L3-resident). Unrolled x2. ----
__global__ __launch_bounds__(256) void aggregate(const unsigned short* __restrict__ xb,
                                                 const int* __restrict__ offs,
                                                 const int* __restrict__ srcbuf,
                                                 unsigned short* __restrict__ hb, int N) {
    int n = blockIdx.x * 4 + (threadIdx.x >> 6);
    if (n >= N) return;
    int lane = threadIdx.x & 63;
    short8 sv = *((const short8*)(xb + (size_t)n * 512) + lane);
    float a[8];
#pragma unroll
    for (int u = 0; u < 8; ++u) a[u] = bf2f((unsigned short)sv[u]);
    int beg = offs[n], end = offs[n + 1];
    int j = beg;
    for (; j + 2 <= end; j += 2) {
        int s0 = srcbuf[j], s1 = srcbuf[j + 1];
        short8 v0 = *((const short8*)(xb + (size_t)s0 * 512) + lane);
        short8 v1 = *((const short8*)(xb + (size_t)s1 * 512) + lane);
#pragma unroll
        for (int u = 0; u < 8; ++u)
            a[u] += bf2f((unsigned short)v0[u]) + bf2f((unsigned short)v1[u]);
    }
    if (j < end) {
        int s0 = srcbuf[j];
        short8 v0 = *((const short8*)(xb + (size_t)s0 * 512) + lane);
#pragma unroll
        for (int u = 0; u < 8; ++u) a[u] += bf2f((unsigned short)v0[u]);
    }
    short8 o;
#pragma unroll
    for (int u = 0; u < 8; ++u) o[u] = (short)f2bf(a[u]);
    *((short8*)(hb + (size_t)n * 512) + lane) = o;
}

// ---- z = h @ Wb^T (bf16 out), stats fused. 128x256 tile, 8 waves (2x4),
//      BK=32, double-buffered 48KB LDS -> 2 blocks/CU (launch_bounds 512,4).
//      Verified minimum 2-phase pipeline: STAGE(next); COMPUTE(cur);
//      __syncthreads() per K-step. BK=32 swizzle: LDS[r][c]=glob[r][c^swz2(r)],
//      swz2(r)=(r&3)^((r>>2)&3); read slot = quad^(l16&3)^((l16>>2)&3). ----
__global__ __launch_bounds__(512, 4) void gemm_bt(const unsigned short* __restrict__ hb,
                                                  const unsigned short* __restrict__ Wb,
                                                  unsigned short* __restrict__ zb,
                                                  float* __restrict__ s1,
                                                  float* __restrict__ s2, int N, int nwg) {
    __shared__ unsigned short As[2][128 * 32];   // rows of 64 B (32 bf16)
    __shared__ unsigned short Bs[2][256 * 32];
    int tid = threadIdx.x;
    int wave = tid >> 6, lane = tid & 63;        // wave 0..7
    int quad = lane >> 4, l16 = lane & 15;
    int rA = lane >> 2;                          // 0..15: row within 16-row strip
    // write-side swizzled chunk for this lane (global k-chunk to fetch)
    int chw = (lane & 3) ^ ((lane >> 2) & 3) ^ ((lane >> 4) & 3);
    // read-side LDS slot (undoes swizzle for logical chunk = quad)
    int slot = quad ^ (l16 & 3) ^ ((l16 >> 2) & 3);

    // bijective XCD swizzle (m204): chunk of ~nwg/8 consecutive work ids per XCD
    int bid = blockIdx.x;
    int q = nwg >> 3, r = nwg & 7;
    int xcd = bid & 7, idx = bid >> 3;
    int wg = (xcd < r) ? (xcd * (q + 1) + idx) : (r * (q + 1) + (xcd - r) * q + idx);
    int row0 = (wg >> 1) * 128;  // col-fastest: 2 col-blocks of one A-panel adjacent
    int col0 = (wg & 1) * 256;
    int wr = (wave >> 2) * 64, wc = (wave & 3) * 64;   // 2x4 wave grid, 64x64 each

    floatx4 acc[4][4] = {};

    // per-lane global base: row (row0 + rA), swizzled 16B chunk chw
    const unsigned short* aG = hb + (size_t)(row0 + rA) * 512 + chw * 8;
    const unsigned short* bG = Wb + (size_t)(col0 + rA) * 512 + chw * 8;

#define STAGE(nb, k0)                                                                   \
    {                                                                                   \
        /* A: 8 strips x 16 rows = 128; strip = wave (1 gload/wave) */                  \
        /* rows may run past N by <48: land in Wb region (finite) — guarded on use */   \
        gload16(aG + (size_t)wave * 16 * 512 + (k0), As[nb] + wave * 512);              \
        _Pragma("unroll")                                                               \
        for (int p = 0; p < 2; ++p) {                                                   \
            int sB = wave * 2 + p;               /* 0..15 */                            \
            gload16(bG + (size_t)sB * 16 * 512 + (k0), Bs[nb] + sB * 512);              \
        }                                                                               \
    }

#define COMPUTE(nb)                                                                     \
    {                                                                                   \
        short8 af[4], bfr[4];                                                           \
        _Pragma("unroll")                                                               \
        for (int i = 0; i < 4; ++i) {                                                   \
            af[i]  = *(const short8*)(As[nb] + (wr + i * 16 + l16) * 32 + slot * 8);    \
            bfr[i] = *(const short8*)(Bs[nb] + (wc + i * 16 + l16) * 32 + slot * 8);    \
        }                                                                               \
        _Pragma("unroll")                                                               \
        for (int i = 0; i < 4; ++i)                                                     \
            _Pragma("unroll")                                                           \
            for (int j = 0; j < 4; ++j)                                                 \
                acc[i][j] = __builtin_amdgcn_mfma_f32_16x16x32_bf16(af[i], bfr[j],      \
                                                                    acc[i][j], 0, 0, 0); \
    }

    STAGE(0, 0)
    __syncthreads();                 // tile 0 fully in LDS (vmcnt(0) drain)
    int cur = 0;
#pragma unroll
    for (int t = 0; t < 15; ++t) {
        STAGE(cur ^ 1, (t + 1) * 32) // issue next tile's 3 loads/wave...
        COMPUTE(cur)                 // ...they overlap these 16 MFMAs + ds_reads
        __syncthreads();             // drain: tile t+1 landed; all waves done with cur
        cur ^= 1;
    }
    COMPUTE(cur)                     // tile 15, no prefetch
#undef STAGE
#undef COMPUTE

    // epilogue: C/D layout col=lane&15, row=quad*4+reg; z in bf16; stats per column
    float p1[4] = {0.f, 0.f, 0.f, 0.f}, p2[4] = {0.f, 0.f, 0.f, 0.f};
#pragma unroll
    for (int i = 0; i < 4; ++i) {
        int rl = wr + i * 16 + quad * 4;
#pragma unroll
        for (int j = 0; j < 4; ++j) {
            int col = col0 + wc + j * 16 + l16;
#pragma unroll
            for (int rr = 0; rr < 4; ++rr) {
                int grow = row0 + rl + rr;
                if (grow < N) {
                    float v = acc[i][j][rr];
                    zb[(size_t)grow * 512 + col] = f2bf(v);
                    p1[j] += v;
                    p2[j] += v * v;
                }
            }
        }
    }
#pragma unroll
    for (int j = 0; j < 4; ++j) {
        p1[j] += __shfl_xor(p1[j], 16); p1[j] += __shfl_xor(p1[j], 32);
        p2[j] += __shfl_xor(p2[j], 16); p2[j] += __shfl_xor(p2[j], 32);
    }
    float* f1 = (float*)As;       // reuse LDS: 256 + 256 floats (fits in As)
    float* f2 = f1 + 256;
    __syncthreads();              // all waves past final COMPUTE before LDS reuse
    if (tid < 512) f1[tid] = 0.f; // zeroes both f1 and f2 (512 threads)
    __syncthreads();
    if (quad == 0) {
#pragma unroll
        for (int j = 0; j < 4; ++j) {
            atomicAdd(&f1[wc + j * 16 + l16], p1[j]);
            atomicAdd(&f2[wc + j * 16 + l16], p2[j]);
        }
    }
    __syncthreads();
    if (tid < 256) {
        unsafeAtomicAdd(&s1[col0 + tid], f1[tid]);
        unsafeAtomicAdd(&s2[col0 + tid], f2[tid]);
    }
}

__global__ void finalize(const float* __restrict__ s1, const float* __restrict__ s2,
                         const float* __restrict__ gamma, const float* __restrict__ beta,
                         float* __restrict__ scale, float* __restrict__ shift, int N) {
    int c = threadIdx.x;  // 512
    float inv = 1.f / (float)N;
    float mean = s1[c] * inv;
    float var = s2[c] * inv - mean * mean;
    if (var < 0.f) var = 0.f;
    float sc = gamma[c] * rsqrtf(var + 1e-5f);
    scale[c] = sc;
    shift[c] = beta[c] - mean * sc;
}

// ---- out = zb * scale[col] + shift[col]; zb bf16 -> out fp32 ----
__global__ __launch_bounds__(256) void bn_apply(const ushort4* __restrict__ zb,
                                                float4* __restrict__ out,
                                                const float4* __restrict__ scale,
                                                const float4* __restrict__ shift, int n4) {
    int i = blockIdx.x * 256 + threadIdx.x;
    if (i >= n4) return;
    int c4 = i & 127;   // 512/4 groups per row
    ushort4 u = zb[i];
    float4 sc = scale[c4], sh = shift[c4];
    float4 v;
    v.x = __uint_as_float((unsigned)u.x << 16) * sc.x + sh.x;
    v.y = __uint_as_float((unsigned)u.y << 16) * sc.y + sh.y;
    v.z = __uint_as_float((unsigned)u.z << 16) * sc.z + sh.z;
    v.w = __uint_as_float((unsigned)u.w << 16) * sc.w + sh.w;
    out[i] = v;
}

extern "C" void kernel_launch(void* const* d_in, const int* in_sizes, int n_in,
                              void* d_out, int out_size, void* d_ws, size_t ws_size,
                              hipStream_t stream) {
    const float* x     = (const float*)d_in[0];
    const int*   ei    = (const int*)d_in[1];
    const float* W     = (const float*)d_in[3];
    const float* gamma = (const float*)d_in[5];
    const float* beta  = (const float*)d_in[6];
    float* out = (float*)d_out;

    int N = in_sizes[0] / 512;   // 50000
    int E = in_sizes[1] / 2;     // 160000

    char* ws = (char*)d_ws;
    size_t off = 0;
    unsigned short* hb = (unsigned short*)(ws + off); off += (size_t)N * 512 * 2;
    unsigned short* Wb = (unsigned short*)(ws + off); off += 512 * 512 * 2;
    float* s1    = (float*)(ws + off); off += 2048;
    float* s2    = (float*)(ws + off); off += 2048;
    float* scale = (float*)(ws + off); off += 2048;
    float* shift = (float*)(ws + off); off += 2048;
    int*   flag  = (int*)(ws + off);   off += 256;
    int*   bsum  = (int*)(ws + off);   off += 256;   // 64 block sums for grid scan
    // prep buffers: own region (live until aggregate ends)
    int*   deg    = (int*)(ws + off);  off += (size_t)N * 4;   // deg+cursor contiguous
    int*   cursor = (int*)(ws + off);  off += (size_t)N * 4;   // (conv_w zeroes both)
    off = (off + 255) & ~(size_t)255;
    int*   offs   = (int*)(ws + off);  off += (size_t)(N + 1) * 4;
    off = (off + 255) & ~(size_t)255;
    int*   srcbuf = (int*)(ws + off);  off += (size_t)E * 4;
    off = (off + 255) & ~(size_t)255;
    // union: xb (conv_x..aggregate) | zb (gemm..bn_apply)
    unsigned short* xb = (unsigned short*)(ws + off);
    unsigned short* zb = (unsigned short*)(ws + off);

    int n4 = N * 128;            // float4 / ushort4 count of [N,512]
    int n8 = N * 64;             // short8 count of [N,512]
    int RB = (N + 127) / 128;    // 391 row-blocks
    int nwg = RB * 2;            // 782 workgroups (2 col-blocks of 256)
    int nb = (N + 1023) / 1024;  // 49 scan blocks (<= 64)

    hipLaunchKernelGGL(detect_dtype, dim3(1), dim3(256), 0, stream, ei, flag);
    hipLaunchKernelGGL(conv_w, dim3(256), dim3(256), 0, stream, W, Wb, s1, deg, 2 * N);
    hipLaunchKernelGGL(conv_x, dim3((n8 + 255) / 256), dim3(256), 0, stream, x, xb, n8);
    hipLaunchKernelGGL(deg_count, dim3((E + 255) / 256), dim3(256), 0, stream, ei, flag, deg, E, N);
    hipLaunchKernelGGL(scan_blk, dim3(nb), dim3(1024), 0, stream, deg, offs, bsum, N);
    hipLaunchKernelGGL(scan_fin, dim3(nb), dim3(1024), 0, stream, offs, bsum, N, nb);
    hipLaunchKernelGGL(bucket_fill, dim3((E + 255) / 256), dim3(256), 0, stream,
                       ei, flag, offs, cursor, srcbuf, E, N);
    hipLaunchKernelGGL(aggregate, dim3((N + 3) / 4), dim3(256), 0, stream,
                       xb, offs, srcbuf, hb, N);
    hipLaunchKernelGGL(gemm_bt, dim3(nwg), dim3(512), 0, stream,
                       hb, Wb, zb, s1, s2, N, nwg);
    hipLaunchKernelGGL(finalize, dim3(1), dim3(512), 0, stream, s1, s2, gamma, beta, scale, shift, N);
    hipLaunchKernelGGL(bn_apply, dim3((n4 + 255) / 256), dim3(256), 0, stream,
                       (const ushort4*)zb, (float4*)out, (const float4*)scale, (const float4*)shift, n4);
}

// Round 10
// 319.789 us; speedup vs baseline: 1.0023x; 1.0023x over previous
//
#include <hip/hip_runtime.h>
#include <hip/hip_bf16.h>

// GIN encoder: out = BN_train( (x + scatter_sum(x[src]->dst)) @ W^T + b ), b cancels in BN.
// N=50000, F=H=512, E=160000.
// R14 = R13 resubmitted verbatim (R13 bench died to "container failed twice" —
//      same infra signature as R11; R12==R11 verbatim resubmit ran green.
//      Re-audit of prep0/edges/bn_apply found no fault surface.)
// R13: launch-count reduction 11 -> 8 (counters: all kernels <59 us yet total
//      320 -> ~130 us is dispatch gaps at ~11 us each). Fusions, all keeping
//      verified inner loops byte-identical:
//        prep0  = conv_w + conv_x + zero(deg,cursor,s1,s2)   (grid-stride)
//        edges  = detect (block-local, redundant) + deg_count
//        bn_apply absorbs finalize (per-block scale/shift into LDS)
//      scan_blk/scan_fin/bucket_fill/aggregate/gemm(R12 128x256/BK=32) unchanged.
// ws: hb[N*512 bf16] | Wb[512*512 bf16] | s1|s2|scale|shift | flag | bsum[64] |
//     deg[N] cursor[N] offs[N+1] srcbuf[E] | union{ xb | zb }[N*512 bf16]  (~105 MB)

typedef __attribute__((ext_vector_type(8))) short short8;
typedef __attribute__((ext_vector_type(4))) float floatx4;

static __device__ __forceinline__ unsigned short f2bf(float f) {
    unsigned int u = __float_as_uint(f);
    u += 0x7FFFu + ((u >> 16) & 1u);   // round-to-nearest-even
    return (unsigned short)(u >> 16);
}

static __device__ __forceinline__ float bf2f(unsigned short v) {
    return __uint_as_float((unsigned)v << 16);
}

static __device__ __forceinline__ void gload16(const void* g, void* l) {
    __builtin_amdgcn_global_load_lds(
        (const __attribute__((address_space(1))) unsigned int*)g,
        (__attribute__((address_space(3))) unsigned int*)l, 16, 0, 0);
}

static __device__ __forceinline__ void load_edge(const int* ei, int flag, int E, int e,
                                                 int& s, int& d) {
    if (flag) {
        const long long* e64 = (const long long*)ei;
        s = (int)e64[e];
        d = (int)e64[E + e];
    } else {
        s = ei[e];
        d = ei[E + e];
    }
}

// ---- prep0: W fp32->bf16, x fp32->bf16, zero deg/cursor/s1/s2. Grid-stride. ----
__global__ __launch_bounds__(256) void prep0(const float* __restrict__ W,
                                             unsigned short* __restrict__ Wb,
                                             const float* __restrict__ x,
                                             unsigned short* __restrict__ xb,
                                             float* __restrict__ stats /*1024 floats*/,
                                             int* __restrict__ dz, int ndz, int n8) {
    int gid = blockIdx.x * 256 + threadIdx.x;
    int stride = gridDim.x * 256;
    if (gid < 1024) stats[gid] = 0.f;                 // zero s1+s2
    for (int k = gid; k < ndz; k += stride) dz[k] = 0; // zero deg+cursor
    for (int i = gid; i < 65536; i += stride) {        // W: 65536 float4
        float4 v = ((const float4*)W)[i];
        ushort4 u;
        u.x = f2bf(v.x); u.y = f2bf(v.y); u.z = f2bf(v.z); u.w = f2bf(v.w);
        ((ushort4*)Wb)[i] = u;
    }
    for (int i = gid; i < n8; i += stride) {           // x: n8 short8
        float4 v0 = ((const float4*)x)[2 * i];
        float4 v1 = ((const float4*)x)[2 * i + 1];
        short8 o;
        o[0] = (short)f2bf(v0.x); o[1] = (short)f2bf(v0.y);
        o[2] = (short)f2bf(v0.z); o[3] = (short)f2bf(v0.w);
        o[4] = (short)f2bf(v1.x); o[5] = (short)f2bf(v1.y);
        o[6] = (short)f2bf(v1.z); o[7] = (short)f2bf(v1.w);
        ((short8*)xb)[i] = o;
    }
}

// ---- edges: block-local dtype detect (same 256 odd words as before, L2-hot,
//      deterministic across blocks) + grid-stride per-dst degree count. ----
__global__ __launch_bounds__(256) void edges(const int* __restrict__ ei,
                                             int* __restrict__ flag,
                                             int* __restrict__ deg, int E, int N) {
    __shared__ int any_nz;
    if (threadIdx.x == 0) any_nz = 0;
    __syncthreads();
    if (ei[2 * threadIdx.x + 1] != 0) atomicOr(&any_nz, 1);
    __syncthreads();
    int f = (any_nz == 0) ? 1 : 0;   // 1 => int64 layout
    if (blockIdx.x == 0 && threadIdx.x == 0) *flag = f;   // for bucket_fill
    int stride = gridDim.x * 256;
    for (int e = blockIdx.x * 256 + threadIdx.x; e < E; e += stride) {
        int s, d;
        load_edge(ei, f, E, e, s, d);
        if ((unsigned)d < (unsigned)N) atomicAdd(&deg[d], 1);
    }
}

// ---- grid scan, part 1: per-block LDS scan of 1024-elem chunk ----
__global__ __launch_bounds__(1024) void scan_blk(const int* __restrict__ deg,
                                                 int* __restrict__ offs,
                                                 int* __restrict__ bsum, int N) {
    __shared__ int s[1024];
    int t = threadIdx.x;
    int g = blockIdx.x * 1024 + t;
    int v = (g < N) ? deg[g] : 0;
    s[t] = v;
    __syncthreads();
    for (int d = 1; d < 1024; d <<= 1) {
        int u = (t >= d) ? s[t - d] : 0;
        __syncthreads();
        s[t] += u;
        __syncthreads();
    }
    if (g < N) offs[g] = s[t] - v;          // exclusive, missing block offset
    if (t == 1023) bsum[blockIdx.x] = s[1023];
}

// ---- grid scan, part 2: add prefix of block sums (wave-0 butterfly) ----
__global__ __launch_bounds__(1024) void scan_fin(int* __restrict__ offs,
                                                 const int* __restrict__ bsum,
                                                 int N, int nb) {
    __shared__ int sh_pre, sh_tot;
    int t = threadIdx.x, b = blockIdx.x;
    if (t < 64) {                            // one full wave; nb <= 64
        int v = (t < nb) ? bsum[t] : 0;
        int p = (t < b) ? v : 0;
#pragma unroll
        for (int d = 1; d < 64; d <<= 1) { p += __shfl_xor(p, d); v += __shfl_xor(v, d); }
        if (t == 0) { sh_pre = p; sh_tot = v; }
    }
    __syncthreads();
    int g = b * 1024 + t;
    if (g < N) offs[g] += sh_pre;
    if (b == nb - 1 && t == 0) offs[N] = sh_tot;
}

// ---- scatter src indices into dst buckets ----
__global__ __launch_bounds__(256) void bucket_fill(const int* __restrict__ ei,
                                                   const int* __restrict__ flag,
                                                   const int* __restrict__ offs,
                                                   int* __restrict__ cursor,
                                                   int* __restrict__ srcbuf, int E, int N) {
    int e = blockIdx.x * 256 + threadIdx.x;
    if (e >= E) return;
    int s, d;
    load_edge(ei, *flag, E, e, s, d);
    if ((unsigned)d >= (unsigned)N || (unsigned)s >= (unsigned)N) return;
    int pos = offs[d] + atomicAdd(&cursor[d], 1);
    srcbuf[pos] = s;
}

// ---- h[n] = bf16( xb[n] + sum_{s in bucket(n)} xb[s] ), fp32 accum.
//      One wave per row: 64 lanes x 8 bf16 = 1024 B per row read, coalesced.
//      Gathers hit L3 (xb = 51.2 MB fully L3-resident). Unrolled x2. ----
__global__ __launch_bounds__(256) void aggregate(const unsigned short* __restrict__ xb,
                                                 const int* __restrict__ offs,
                                                 const int* __restrict__ srcbuf,
                                                 unsigned short* __restrict__ hb, int N) {
    int n = blockIdx.x * 4 + (threadIdx.x >> 6);
    if (n >= N) return;
    int lane = threadIdx.x & 63;
    short8 sv = *((const short8*)(xb + (size_t)n * 512) + lane);
    float a[8];
#pragma unroll
    for (int u = 0; u < 8; ++u) a[u] = bf2f((unsigned short)sv[u]);
    int beg = offs[n], end = offs[n + 1];
    int j = beg;
    for (; j + 2 <= end; j += 2) {
        int s0 = srcbuf[j], s1 = srcbuf[j + 1];
        short8 v0 = *((const short8*)(xb + (size_t)s0 * 512) + lane);
        short8 v1 = *((const short8*)(xb + (size_t)s1 * 512) + lane);
#pragma unroll
        for (int u = 0; u < 8; ++u)
            a[u] += bf2f((unsigned short)v0[u]) + bf2f((unsigned short)v1[u]);
    }
    if (j < end) {
        int s0 = srcbuf[j];
        short8 v0 = *((const short8*)(xb + (size_t)s0 * 512) + lane);
#pragma unroll
        for (int u = 0; u < 8; ++u) a[u] += bf2f((unsigned short)v0[u]);
    }
    short8 o;
#pragma unroll
    for (int u = 0; u < 8; ++u) o[u] = (short)f2bf(a[u]);
    *((short8*)(hb + (size_t)n * 512) + lane) = o;
}

// ---- z = h @ Wb^T (bf16 out), stats fused. 128x256 tile, 8 waves (2x4),
//      BK=32, double-buffered 48KB LDS, 2 blocks/CU. Verified minimum 2-phase
//      pipeline: STAGE(next); COMPUTE(cur); __syncthreads() per K-step. ----
__global__ __launch_bounds__(512, 4) void gemm_bt(const unsigned short* __restrict__ hb,
                                                  const unsigned short* __restrict__ Wb,
                                                  unsigned short* __restrict__ zb,
                                                  float* __restrict__ s1,
                                                  float* __restrict__ s2, int N, int nwg) {
    __shared__ unsigned short As[2][128 * 32];   // rows of 64 B (32 bf16)
    __shared__ unsigned short Bs[2][256 * 32];
    int tid = threadIdx.x;
    int wave = tid >> 6, lane = tid & 63;        // wave 0..7
    int quad = lane >> 4, l16 = lane & 15;
    int rA = lane >> 2;                          // 0..15: row within 16-row strip
    int chw = (lane & 3) ^ ((lane >> 2) & 3) ^ ((lane >> 4) & 3);
    int slot = quad ^ (l16 & 3) ^ ((l16 >> 2) & 3);

    int bid = blockIdx.x;
    int q = nwg >> 3, r = nwg & 7;
    int xcd = bid & 7, idx = bid >> 3;
    int wg = (xcd < r) ? (xcd * (q + 1) + idx) : (r * (q + 1) + (xcd - r) * q + idx);
    int row0 = (wg >> 1) * 128;
    int col0 = (wg & 1) * 256;
    int wr = (wave >> 2) * 64, wc = (wave & 3) * 64;

    floatx4 acc[4][4] = {};

    const unsigned short* aG = hb + (size_t)(row0 + rA) * 512 + chw * 8;
    const unsigned short* bG = Wb + (size_t)(col0 + rA) * 512 + chw * 8;

#define STAGE(nb, k0)                                                                   \
    {                                                                                   \
        gload16(aG + (size_t)wave * 16 * 512 + (k0), As[nb] + wave * 512);              \
        _Pragma("unroll")                                                               \
        for (int p = 0; p < 2; ++p) {                                                   \
            int sB = wave * 2 + p;                                                      \
            gload16(bG + (size_t)sB * 16 * 512 + (k0), Bs[nb] + sB * 512);              \
        }                                                                               \
    }

#define COMPUTE(nb)                                                                     \
    {                                                                                   \
        short8 af[4], bfr[4];                                                           \
        _Pragma("unroll")                                                               \
        for (int i = 0; i < 4; ++i) {                                                   \
            af[i]  = *(const short8*)(As[nb] + (wr + i * 16 + l16) * 32 + slot * 8);    \
            bfr[i] = *(const short8*)(Bs[nb] + (wc + i * 16 + l16) * 32 + slot * 8);    \
        }                                                                               \
        _Pragma("unroll")                                                               \
        for (int i = 0; i < 4; ++i)                                                     \
            _Pragma("unroll")                                                           \
            for (int j = 0; j < 4; ++j)                                                 \
                acc[i][j] = __builtin_amdgcn_mfma_f32_16x16x32_bf16(af[i], bfr[j],      \
                                                                    acc[i][j], 0, 0, 0); \
    }

    STAGE(0, 0)
    __syncthreads();
    int cur = 0;
#pragma unroll
    for (int t = 0; t < 15; ++t) {
        STAGE(cur ^ 1, (t + 1) * 32)
        COMPUTE(cur)
        __syncthreads();
        cur ^= 1;
    }
    COMPUTE(cur)
#undef STAGE
#undef COMPUTE

    float p1[4] = {0.f, 0.f, 0.f, 0.f}, p2[4] = {0.f, 0.f, 0.f, 0.f};
#pragma unroll
    for (int i = 0; i < 4; ++i) {
        int rl = wr + i * 16 + quad * 4;
#pragma unroll
        for (int j = 0; j < 4; ++j) {
            int col = col0 + wc + j * 16 + l16;
#pragma unroll
            for (int rr = 0; rr < 4; ++rr) {
                int grow = row0 + rl + rr;
                if (grow < N) {
                    float v = acc[i][j][rr];
                    zb[(size_t)grow * 512 + col] = f2bf(v);
                    p1[j] += v;
                    p2[j] += v * v;
                }
            }
        }
    }
#pragma unroll
    for (int j = 0; j < 4; ++j) {
        p1[j] += __shfl_xor(p1[j], 16); p1[j] += __shfl_xor(p1[j], 32);
        p2[j] += __shfl_xor(p2[j], 16); p2[j] += __shfl_xor(p2[j], 32);
    }
    float* f1 = (float*)As;       // reuse LDS: 256 + 256 floats
    float* f2 = f1 + 256;
    __syncthreads();
    if (tid < 512) f1[tid] = 0.f;
    __syncthreads();
    if (quad == 0) {
#pragma unroll
        for (int j = 0; j < 4; ++j) {
            atomicAdd(&f1[wc + j * 16 + l16], p1[j]);
            atomicAdd(&f2[wc + j * 16 + l16], p2[j]);
        }
    }
    __syncthreads();
    if (tid < 256) {
        unsafeAtomicAdd(&s1[col0 + tid], f1[tid]);
        unsafeAtomicAdd(&s2[col0 + tid], f2[tid]);
    }
}

// ---- bn_apply (finalize fused): per-block scale/shift from s1/s2 in LDS,
//      then grid-stride apply: out = zb * scale[col] + shift[col]. ----
__global__ __launch_bounds__(256) void bn_apply(const ushort4* __restrict__ zb,
                                                float4* __restrict__ out,
                                                const float* __restrict__ s1,
                                                const float* __restrict__ s2,
                                                const float* __restrict__ gamma,
                                                const float* __restrict__ beta,
                                                int n4, int N) {
    __shared__ float sc_sh[512], sh_sh[512];
    int t = threadIdx.x;
    float inv = 1.f / (float)N;
    for (int c = t; c < 512; c += 256) {
        float mean = s1[c] * inv;
        float var = s2[c] * inv - mean * mean;
        if (var < 0.f) var = 0.f;
        float sc = gamma[c] * rsqrtf(var + 1e-5f);
        sc_sh[c] = sc;
        sh_sh[c] = beta[c] - mean * sc;
    }
    __syncthreads();
    int stride = gridDim.x * 256;
    for (int i = blockIdx.x * 256 + t; i < n4; i += stride) {
        int c4 = (i & 127) * 4;
        ushort4 u = zb[i];
        float4 v;
        v.x = bf2f(u.x) * sc_sh[c4 + 0] + sh_sh[c4 + 0];
        v.y = bf2f(u.y) * sc_sh[c4 + 1] + sh_sh[c4 + 1];
        v.z = bf2f(u.z) * sc_sh[c4 + 2] + sh_sh[c4 + 2];
        v.w = bf2f(u.w) * sc_sh[c4 + 3] + sh_sh[c4 + 3];
        out[i] = v;
    }
}

extern "C" void kernel_launch(void* const* d_in, const int* in_sizes, int n_in,
                              void* d_out, int out_size, void* d_ws, size_t ws_size,
                              hipStream_t stream) {
    const float* x     = (const float*)d_in[0];
    const int*   ei    = (const int*)d_in[1];
    const float* W     = (const float*)d_in[3];
    const float* gamma = (const float*)d_in[5];
    const float* beta  = (const float*)d_in[6];
    float* out = (float*)d_out;

    int N = in_sizes[0] / 512;   // 50000
    int E = in_sizes[1] / 2;     // 160000

    char* ws = (char*)d_ws;
    size_t off = 0;
    unsigned short* hb = (unsigned short*)(ws + off); off += (size_t)N * 512 * 2;
    unsigned short* Wb = (unsigned short*)(ws + off); off += 512 * 512 * 2;
    float* s1    = (float*)(ws + off); off += 2048;
    float* s2    = (float*)(ws + off); off += 2048;
    float* scale = (float*)(ws + off); off += 2048;   // unused (kept for layout stability)
    float* shift = (float*)(ws + off); off += 2048;   // unused
    int*   flag  = (int*)(ws + off);   off += 256;
    int*   bsum  = (int*)(ws + off);   off += 256;    // 64 block sums for grid scan
    int*   deg    = (int*)(ws + off);  off += (size_t)N * 4;   // deg+cursor contiguous
    int*   cursor = (int*)(ws + off);  off += (size_t)N * 4;   // (prep0 zeroes both)
    off = (off + 255) & ~(size_t)255;
    int*   offs   = (int*)(ws + off);  off += (size_t)(N + 1) * 4;
    off = (off + 255) & ~(size_t)255;
    int*   srcbuf = (int*)(ws + off);  off += (size_t)E * 4;
    off = (off + 255) & ~(size_t)255;
    unsigned short* xb = (unsigned short*)(ws + off);   // union with zb
    unsigned short* zb = (unsigned short*)(ws + off);

    int n4 = N * 128;            // float4 / ushort4 count of [N,512]
    int n8 = N * 64;             // short8 count of [N,512]
    int RB = (N + 127) / 128;    // 391 row-blocks
    int nwg = RB * 2;            // 782 workgroups (2 col-blocks of 256)
    int nb = (N + 1023) / 1024;  // 49 scan blocks (<= 64)
    (void)scale; (void)shift;

    hipLaunchKernelGGL(prep0, dim3(2048), dim3(256), 0, stream,
                       W, Wb, x, xb, s1, deg, 2 * N, n8);
    hipLaunchKernelGGL(edges, dim3((E + 255) / 256), dim3(256), 0, stream,
                       ei, flag, deg, E, N);
    hipLaunchKernelGGL(scan_blk, dim3(nb), dim3(1024), 0, stream, deg, offs, bsum, N);
    hipLaunchKernelGGL(scan_fin, dim3(nb), dim3(1024), 0, stream, offs, bsum, N, nb);
    hipLaunchKernelGGL(bucket_fill, dim3((E + 255) / 256), dim3(256), 0, stream,
                       ei, flag, offs, cursor, srcbuf, E, N);
    hipLaunchKernelGGL(aggregate, dim3((N + 3) / 4), dim3(256), 0, stream,
                       xb, offs, srcbuf, hb, N);
    hipLaunchKernelGGL(gemm_bt, dim3(nwg), dim3(512), 0, stream,
                       hb, Wb, zb, s1, s2, N, nwg);
    hipLaunchKernelGGL(bn_apply, dim3(2048), dim3(256), 0, stream,
                       (const ushort4*)zb, (float4*)out, s1, s2, gamma, beta, n4, N);
}

// Round 11
// 316.578 us; speedup vs baseline: 1.0124x; 1.0101x over previous
//
#include <hip/hip_runtime.h>
#include <hip/hip_bf16.h>

// GIN encoder: out = BN_train( (x + scatter_sum(x[src]->dst)) @ W^T + b ), b cancels in BN.
// N=50000, F=H=512, E=160000.
// R15: revert gemm to R10's 256x256/16w/BK=64 variant — the only gemm with
//      measured 0 bank conflicts AND <58.7 us (R10/R12 top-5 cutoff). R14's
//      BK=32 swizzle had 3.2M conflicts/dispatch (row*16 mod 32 takes 2 values
//      at 64B rows -> ~4-way conflict on every ds_read_b128) and ran 70.8 us.
//      Launch fusion (11->8, R13/R14) kept: null result but harmless.
// ws: hb[N*512 bf16] | Wb[512*512 bf16] | s1|s2|scale|shift | flag | bsum[64] |
//     deg[N] cursor[N] offs[N+1] srcbuf[E] | union{ xb | zb }[N*512 bf16]  (~105 MB)

typedef __attribute__((ext_vector_type(8))) short short8;
typedef __attribute__((ext_vector_type(4))) float floatx4;

static __device__ __forceinline__ unsigned short f2bf(float f) {
    unsigned int u = __float_as_uint(f);
    u += 0x7FFFu + ((u >> 16) & 1u);   // round-to-nearest-even
    return (unsigned short)(u >> 16);
}

static __device__ __forceinline__ float bf2f(unsigned short v) {
    return __uint_as_float((unsigned)v << 16);
}

static __device__ __forceinline__ void gload16(const void* g, void* l) {
    __builtin_amdgcn_global_load_lds(
        (const __attribute__((address_space(1))) unsigned int*)g,
        (__attribute__((address_space(3))) unsigned int*)l, 16, 0, 0);
}

static __device__ __forceinline__ void load_edge(const int* ei, int flag, int E, int e,
                                                 int& s, int& d) {
    if (flag) {
        const long long* e64 = (const long long*)ei;
        s = (int)e64[e];
        d = (int)e64[E + e];
    } else {
        s = ei[e];
        d = ei[E + e];
    }
}

// ---- prep0: W fp32->bf16, x fp32->bf16, zero deg/cursor/s1/s2. Grid-stride. ----
__global__ __launch_bounds__(256) void prep0(const float* __restrict__ W,
                                             unsigned short* __restrict__ Wb,
                                             const float* __restrict__ x,
                                             unsigned short* __restrict__ xb,
                                             float* __restrict__ stats /*1024 floats*/,
                                             int* __restrict__ dz, int ndz, int n8) {
    int gid = blockIdx.x * 256 + threadIdx.x;
    int stride = gridDim.x * 256;
    if (gid < 1024) stats[gid] = 0.f;                 // zero s1+s2
    for (int k = gid; k < ndz; k += stride) dz[k] = 0; // zero deg+cursor
    for (int i = gid; i < 65536; i += stride) {        // W: 65536 float4
        float4 v = ((const float4*)W)[i];
        ushort4 u;
        u.x = f2bf(v.x); u.y = f2bf(v.y); u.z = f2bf(v.z); u.w = f2bf(v.w);
        ((ushort4*)Wb)[i] = u;
    }
    for (int i = gid; i < n8; i += stride) {           // x: n8 short8
        float4 v0 = ((const float4*)x)[2 * i];
        float4 v1 = ((const float4*)x)[2 * i + 1];
        short8 o;
        o[0] = (short)f2bf(v0.x); o[1] = (short)f2bf(v0.y);
        o[2] = (short)f2bf(v0.z); o[3] = (short)f2bf(v0.w);
        o[4] = (short)f2bf(v1.x); o[5] = (short)f2bf(v1.y);
        o[6] = (short)f2bf(v1.z); o[7] = (short)f2bf(v1.w);
        ((short8*)xb)[i] = o;
    }
}

// ---- edges: block-local dtype detect + grid-stride per-dst degree count. ----
__global__ __launch_bounds__(256) void edges(const int* __restrict__ ei,
                                             int* __restrict__ flag,
                                             int* __restrict__ deg, int E, int N) {
    __shared__ int any_nz;
    if (threadIdx.x == 0) any_nz = 0;
    __syncthreads();
    if (ei[2 * threadIdx.x + 1] != 0) atomicOr(&any_nz, 1);
    __syncthreads();
    int f = (any_nz == 0) ? 1 : 0;   // 1 => int64 layout
    if (blockIdx.x == 0 && threadIdx.x == 0) *flag = f;   // for bucket_fill
    int stride = gridDim.x * 256;
    for (int e = blockIdx.x * 256 + threadIdx.x; e < E; e += stride) {
        int s, d;
        load_edge(ei, f, E, e, s, d);
        if ((unsigned)d < (unsigned)N) atomicAdd(&deg[d], 1);
    }
}

// ---- grid scan, part 1: per-block LDS scan of 1024-elem chunk ----
__global__ __launch_bounds__(1024) void scan_blk(const int* __restrict__ deg,
                                                 int* __restrict__ offs,
                                                 int* __restrict__ bsum, int N) {
    __shared__ int s[1024];
    int t = threadIdx.x;
    int g = blockIdx.x * 1024 + t;
    int v = (g < N) ? deg[g] : 0;
    s[t] = v;
    __syncthreads();
    for (int d = 1; d < 1024; d <<= 1) {
        int u = (t >= d) ? s[t - d] : 0;
        __syncthreads();
        s[t] += u;
        __syncthreads();
    }
    if (g < N) offs[g] = s[t] - v;          // exclusive, missing block offset
    if (t == 1023) bsum[blockIdx.x] = s[1023];
}

// ---- grid scan, part 2: add prefix of block sums (wave-0 butterfly) ----
__global__ __launch_bounds__(1024) void scan_fin(int* __restrict__ offs,
                                                 const int* __restrict__ bsum,
                                                 int N, int nb) {
    __shared__ int sh_pre, sh_tot;
    int t = threadIdx.x, b = blockIdx.x;
    if (t < 64) {                            // one full wave; nb <= 64
        int v = (t < nb) ? bsum[t] : 0;
        int p = (t < b) ? v : 0;
#pragma unroll
        for (int d = 1; d < 64; d <<= 1) { p += __shfl_xor(p, d); v += __shfl_xor(v, d); }
        if (t == 0) { sh_pre = p; sh_tot = v; }
    }
    __syncthreads();
    int g = b * 1024 + t;
    if (g < N) offs[g] += sh_pre;
    if (b == nb - 1 && t == 0) offs[N] = sh_tot;
}

// ---- scatter src indices into dst buckets ----
__global__ __launch_bounds__(256) void bucket_fill(const int* __restrict__ ei,
                                                   const int* __restrict__ flag,
                                                   const int* __restrict__ offs,
                                                   int* __restrict__ cursor,
                                                   int* __restrict__ srcbuf, int E, int N) {
    int e = blockIdx.x * 256 + threadIdx.x;
    if (e >= E) return;
    int s, d;
    load_edge(ei, *flag, E, e, s, d);
    if ((unsigned)d >= (unsigned)N || (unsigned)s >= (unsigned)N) return;
    int pos = offs[d] + atomicAdd(&cursor[d], 1);
    srcbuf[pos] = s;
}

// ---- h[n] = bf16( xb[n] + sum_{s in bucket(n)} xb[s] ), fp32 accum. ----
__global__ __launch_bounds__(256) void aggregate(const unsigned short* __restrict__ xb,
                                                 const int* __restrict__ offs,
                                                 const int* __restrict__ srcbuf,
                                                 unsigned short* __restrict__ hb, int N) {
    int n = blockIdx.x * 4 + (threadIdx.x >> 6);
    if (n >= N) return;
    int lane = threadIdx.x & 63;
    short8 sv = *((const short8*)(xb + (size_t)n * 512) + lane);
    float a[8];
#pragma unroll
    for (int u = 0; u < 8; ++u) a[u] = bf2f((unsigned short)sv[u]);
    int beg = offs[n], end = offs[n + 1];
    int j = beg;
    for (; j + 2 <= end; j += 2) {
        int s0 = srcbuf[j], s1 = srcbuf[j + 1];
        short8 v0 = *((const short8*)(xb + (size_t)s0 * 512) + lane);
        short8 v1 = *((const short8*)(xb + (size_t)s1 * 512) + lane);
#pragma unroll
        for (int u = 0; u < 8; ++u)
            a[u] += bf2f((unsigned short)v0[u]) + bf2f((unsigned short)v1[u]);
    }
    if (j < end) {
        int s0 = srcbuf[j];
        short8 v0 = *((const short8*)(xb + (size_t)s0 * 512) + lane);
#pragma unroll
        for (int u = 0; u < 8; ++u) a[u] += bf2f((unsigned short)v0[u]);
    }
    short8 o;
#pragma unroll
    for (int u = 0; u < 8; ++u) o[u] = (short)f2bf(a[u]);
    *((short8*)(hb + (size_t)n * 512) + lane) = o;
}

// ---- z = h @ Wb^T (bf16 out), stats fused. 256x256 tile, 16 waves (4x4),
//      BK=64, double-buffered 128KB LDS. Measured (R10/R12): 0 bank conflicts,
//      <58.7 us. Verified minimum 2-phase pipeline: STAGE(next); COMPUTE(cur);
//      ONE full-drain __syncthreads() per K-tile. ----
__global__ __launch_bounds__(1024) void gemm_bt(const unsigned short* __restrict__ hb,
                                                const unsigned short* __restrict__ Wb,
                                                unsigned short* __restrict__ zb,
                                                float* __restrict__ s1,
                                                float* __restrict__ s2, int N, int nwg) {
    __shared__ unsigned short As[2][256 * 64];   // row-major, 64 bf16 (128 B) per row
    __shared__ unsigned short Bs[2][256 * 64];
    int tid = threadIdx.x;
    int wave = tid >> 6, lane = tid & 63;        // wave 0..15
    int quad = lane >> 4, l16 = lane & 15;
    int r8 = lane >> 3;          // 0..7: row within this wave's 8-row strip
    int c8 = lane & 7;           // 0..7: 16B chunk within 128B row
    int swz = c8 ^ r8;           // XOR swizzle (applied on global side)

    // bijective XCD swizzle (m204)
    int bid = blockIdx.x;
    int q = nwg >> 3, r = nwg & 7;
    int xcd = bid & 7, idx = bid >> 3;
    int wg = (xcd < r) ? (xcd * (q + 1) + idx) : (r * (q + 1) + (xcd - r) * q + idx);
    int row0 = (wg >> 1) * 256;  // col-fastest: 2 col-blocks of one A-panel adjacent
    int col0 = (wg & 1) * 256;
    int wr = (wave >> 2) * 64, wc = (wave & 3) * 64;   // 4x4 wave grid, 64x64 each

    floatx4 acc[4][4] = {};

    const unsigned short* aG = hb + (size_t)row0 * 512 + swz * 8;
    const unsigned short* bG = Wb + (size_t)col0 * 512 + swz * 8;

#define STAGE(nb, k0)                                                                   \
    {                                                                                   \
        _Pragma("unroll")                                                               \
        for (int p = 0; p < 2; ++p) {                                                   \
            int strip = p * 16 + wave;           /* 0..31 */                            \
            int rt = strip * 8 + r8;             /* tile row 0..255 */                  \
            /* A rows may run past N by <176: land in Wb/stats region — guarded */      \
            gload16(aG + (size_t)rt * 512 + (k0), As[nb] + strip * 512);                \
            gload16(bG + (size_t)rt * 512 + (k0), Bs[nb] + strip * 512);                \
        }                                                                               \
    }

#define COMPUTE(nb)                                                                     \
    {                                                                                   \
        _Pragma("unroll")                                                               \
        for (int kk = 0; kk < 2; ++kk) {                                                \
            short8 af[4], bfr[4];                                                       \
            _Pragma("unroll")                                                           \
            for (int i = 0; i < 4; ++i) {                                               \
                int ch = (kk * 4 + quad) ^ (l16 & 7);                                   \
                af[i]  = *(const short8*)(As[nb] + (wr + i * 16 + l16) * 64 + ch * 8);  \
                bfr[i] = *(const short8*)(Bs[nb] + (wc + i * 16 + l16) * 64 + ch * 8);  \
            }                                                                           \
            _Pragma("unroll")                                                           \
            for (int i = 0; i < 4; ++i)                                                 \
                _Pragma("unroll")                                                       \
                for (int j = 0; j < 4; ++j)                                             \
                    acc[i][j] = __builtin_amdgcn_mfma_f32_16x16x32_bf16(af[i], bfr[j],  \
                                                                        acc[i][j], 0, 0, 0); \
        }                                                                               \
    }

    STAGE(0, 0)
    __syncthreads();                 // tile 0 fully in LDS (vmcnt(0) drain)
    int cur = 0;
#pragma unroll
    for (int t = 0; t < 7; ++t) {
        STAGE(cur ^ 1, (t + 1) * 64) // issue next tile's 4 loads/wave...
        COMPUTE(cur)                 // ...they overlap these 32 MFMAs + ds_reads
        __syncthreads();             // drain: tile t+1 landed; all waves done with cur
        cur ^= 1;
    }
    COMPUTE(cur)                     // tile 7, no prefetch
#undef STAGE
#undef COMPUTE

    // epilogue: C/D layout col=lane&15, row=quad*4+reg; z in bf16; stats per column
    float p1[4] = {0.f, 0.f, 0.f, 0.f}, p2[4] = {0.f, 0.f, 0.f, 0.f};
#pragma unroll
    for (int i = 0; i < 4; ++i) {
        int rl = wr + i * 16 + quad * 4;
#pragma unroll
        for (int j = 0; j < 4; ++j) {
            int col = col0 + wc + j * 16 + l16;
#pragma unroll
            for (int rr = 0; rr < 4; ++rr) {
                int grow = row0 + rl + rr;
                if (grow < N) {
                    float v = acc[i][j][rr];
                    zb[(size_t)grow * 512 + col] = f2bf(v);
                    p1[j] += v;
                    p2[j] += v * v;
                }
            }
        }
    }
#pragma unroll
    for (int j = 0; j < 4; ++j) {
        p1[j] += __shfl_xor(p1[j], 16); p1[j] += __shfl_xor(p1[j], 32);
        p2[j] += __shfl_xor(p2[j], 16); p2[j] += __shfl_xor(p2[j], 32);
    }
    float* f1 = (float*)As;       // reuse LDS: 256 + 256 floats
    float* f2 = f1 + 256;
    __syncthreads();              // all waves past final COMPUTE before LDS reuse
    if (tid < 512) f1[tid] = 0.f; // zeroes both f1 and f2
    __syncthreads();
    if (quad == 0) {
#pragma unroll
        for (int j = 0; j < 4; ++j) {
            atomicAdd(&f1[wc + j * 16 + l16], p1[j]);
            atomicAdd(&f2[wc + j * 16 + l16], p2[j]);
        }
    }
    __syncthreads();
    if (tid < 256) {
        unsafeAtomicAdd(&s1[col0 + tid], f1[tid]);
        unsafeAtomicAdd(&s2[col0 + tid], f2[tid]);
    }
}

// ---- bn_apply (finalize fused): per-block scale/shift from s1/s2 in LDS,
//      then grid-stride apply: out = zb * scale[col] + shift[col]. ----
__global__ __launch_bounds__(256) void bn_apply(const ushort4* __restrict__ zb,
                                                float4* __restrict__ out,
                                                const float* __restrict__ s1,
                                                const float* __restrict__ s2,
                                                const float* __restrict__ gamma,
                                                const float* __restrict__ beta,
                                                int n4, int N) {
    __shared__ float sc_sh[512], sh_sh[512];
    int t = threadIdx.x;
    float inv = 1.f / (float)N;
    for (int c = t; c < 512; c += 256) {
        float mean = s1[c] * inv;
        float var = s2[c] * inv - mean * mean;
        if (var < 0.f) var = 0.f;
        float sc = gamma[c] * rsqrtf(var + 1e-5f);
        sc_sh[c] = sc;
        sh_sh[c] = beta[c] - mean * sc;
    }
    __syncthreads();
    int stride = gridDim.x * 256;
    for (int i = blockIdx.x * 256 + t; i < n4; i += stride) {
        int c4 = (i & 127) * 4;
        ushort4 u = zb[i];
        float4 v;
        v.x = bf2f(u.x) * sc_sh[c4 + 0] + sh_sh[c4 + 0];
        v.y = bf2f(u.y) * sc_sh[c4 + 1] + sh_sh[c4 + 1];
        v.z = bf2f(u.z) * sc_sh[c4 + 2] + sh_sh[c4 + 2];
        v.w = bf2f(u.w) * sc_sh[c4 + 3] + sh_sh[c4 + 3];
        out[i] = v;
    }
}

extern "C" void kernel_launch(void* const* d_in, const int* in_sizes, int n_in,
                              void* d_out, int out_size, void* d_ws, size_t ws_size,
                              hipStream_t stream) {
    const float* x     = (const float*)d_in[0];
    const int*   ei    = (const int*)d_in[1];
    const float* W     = (const float*)d_in[3];
    const float* gamma = (const float*)d_in[5];
    const float* beta  = (const float*)d_in[6];
    float* out = (float*)d_out;

    int N = in_sizes[0] / 512;   // 50000
    int E = in_sizes[1] / 2;     // 160000

    char* ws = (char*)d_ws;
    size_t off = 0;
    unsigned short* hb = (unsigned short*)(ws + off); off += (size_t)N * 512 * 2;
    unsigned short* Wb = (unsigned short*)(ws + off); off += 512 * 512 * 2;
    float* s1    = (float*)(ws + off); off += 2048;
    float* s2    = (float*)(ws + off); off += 2048;
    float* scale = (float*)(ws + off); off += 2048;   // unused (layout stability)
    float* shift = (float*)(ws + off); off += 2048;   // unused
    int*   flag  = (int*)(ws + off);   off += 256;
    int*   bsum  = (int*)(ws + off);   off += 256;    // 64 block sums for grid scan
    int*   deg    = (int*)(ws + off);  off += (size_t)N * 4;   // deg+cursor contiguous
    int*   cursor = (int*)(ws + off);  off += (size_t)N * 4;   // (prep0 zeroes both)
    off = (off + 255) & ~(size_t)255;
    int*   offs   = (int*)(ws + off);  off += (size_t)(N + 1) * 4;
    off = (off + 255) & ~(size_t)255;
    int*   srcbuf = (int*)(ws + off);  off += (size_t)E * 4;
    off = (off + 255) & ~(size_t)255;
    unsigned short* xb = (unsigned short*)(ws + off);   // union with zb
    unsigned short* zb = (unsigned short*)(ws + off);

    int n4 = N * 128;            // float4 / ushort4 count of [N,512]
    int n8 = N * 64;             // short8 count of [N,512]
    int RB = (N + 255) / 256;    // 196 row-blocks
    int nwg = RB * 2;            // 392 workgroups (2 col-blocks of 256)
    int nb = (N + 1023) / 1024;  // 49 scan blocks (<= 64)
    (void)scale; (void)shift;

    hipLaunchKernelGGL(prep0, dim3(2048), dim3(256), 0, stream,
                       W, Wb, x, xb, s1, deg, 2 * N, n8);
    hipLaunchKernelGGL(edges, dim3((E + 255) / 256), dim3(256), 0, stream,
                       ei, flag, deg, E, N);
    hipLaunchKernelGGL(scan_blk, dim3(nb), dim3(1024), 0, stream, deg, offs, bsum, N);
    hipLaunchKernelGGL(scan_fin, dim3(nb), dim3(1024), 0, stream, offs, bsum, N, nb);
    hipLaunchKernelGGL(bucket_fill, dim3((E + 255) / 256), dim3(256), 0, stream,
                       ei, flag, offs, cursor, srcbuf, E, N);
    hipLaunchKernelGGL(aggregate, dim3((N + 3) / 4), dim3(256), 0, stream,
                       xb, offs, srcbuf, hb, N);
    hipLaunchKernelGGL(gemm_bt, dim3(nwg), dim3(1024), 0, stream,
                       hb, Wb, zb, s1, s2, N, nwg);
    hipLaunchKernelGGL(bn_apply, dim3(2048), dim3(256), 0, stream,
                       (const ushort4*)zb, (float4*)out, s1, s2, gamma, beta, n4, N);
}